// Round 2
// baseline (184.585 us; speedup 1.0000x reference)
//
#include <hip/hip_runtime.h>
#include <hip/hip_bf16.h>

// out = x @ (W + 16*(M@N))^T + b  where M(1024x8), N(8x1024) are folded TT cores.
// v3: prep split into P0 (compute M,NT once, 1 block) + P1 (streaming Weff build
// + x cast). GEMM: 256x256 tile, 8 waves (2Mx4N), mfma 32x32x16, BK=32,
// 4-deep LDS pipeline (128KB), counted vmcnt(8), XCD swizzle, 256 blocks = 1/CU.

#define D_DIM 1024
#define BS_ROWS 16384
#define ALPHA_F 16.0f
#define BM 128
#define BN 128

using bf16   = __bf16;
using bf16x8 = __attribute__((ext_vector_type(8))) __bf16;
using bf16x4 = __attribute__((ext_vector_type(4))) __bf16;
using f32x4  = __attribute__((ext_vector_type(4))) float;
using f32x16 = __attribute__((ext_vector_type(16))) float;

#define GPTR(p) (const __attribute__((address_space(1))) void*)(p)
#define SPTR(p) (__attribute__((address_space(3))) void*)(p)

// ---- P0: compute M[1024][8] and NT[1024][8] once (1 block) ------------------
__global__ __launch_bounds__(256) void make_mn_kernel(
    const float* __restrict__ c0, const float* __restrict__ c1,
    const float* __restrict__ c2, const float* __restrict__ c3,
    const float* __restrict__ c4, const float* __restrict__ c5,
    float* __restrict__ Mws, float* __restrict__ NTws)
{
    __shared__ float t2[128 * 9];   // padded stride 9 (bank spread)
    __shared__ float vt[128 * 9];
    const int tid = threadIdx.x;

    // t2[(i2*8+i1)][p2] = sum_p1 c0[0,i1,p1]*c1[p1,i2,p2]
    for (int e = tid; e < 1024; e += 256) {
        int p2 = e & 7, i2i1 = e >> 3;
        int i1 = i2i1 & 7, i2 = i2i1 >> 3;
        float s = 0.f;
        for (int p1 = 0; p1 < 8; ++p1)
            s += c0[i1 * 8 + p1] * c1[p1 * 128 + i2 * 8 + p2];
        t2[i2i1 * 9 + p2] = s;
    }
    __syncthreads();
    // M[d][p3] = sum_p2 t2[i2*8+i1][p2]*c2[p2,i3,p3], d = i3*128+i2*8+i1
    for (int e = tid; e < 8192; e += 256) {
        int p3 = e & 7, d = e >> 3;
        int i1 = d & 7, i2 = (d >> 3) & 15, i3 = d >> 7;
        float s = 0.f;
        for (int p2 = 0; p2 < 8; ++p2)
            s += t2[(i2 * 8 + i1) * 9 + p2] * c2[p2 * 64 + i3 * 8 + p3];
        Mws[e] = s;
    }
    // vt[(n2*8+n3)][p4] = sum_p5 c4[p4,n2,p5]*c5[p5,n3]
    for (int e = tid; e < 1024; e += 256) {
        int p4 = e & 7, nn = e >> 3;
        int n2 = nn >> 3, n3 = nn & 7;
        float s = 0.f;
        for (int p5 = 0; p5 < 8; ++p5)
            s += c4[p4 * 128 + n2 * 8 + p5] * c5[p5 * 8 + n3];
        vt[nn * 9 + p4] = s;
    }
    __syncthreads();
    // NT[o][r3] = sum_p4 c3[r3,n1,p4]*vt[n2n3][p4], o = n1*128+n2*8+n3
    for (int e = tid; e < 8192; e += 256) {
        int r3 = e & 7, o = e >> 3;
        int n1 = o >> 7, nn = o & 127;
        float s = 0.f;
        for (int p4 = 0; p4 < 8; ++p4)
            s += c3[r3 * 64 + n1 * 8 + p4] * vt[nn * 9 + p4];
        NTws[o * 8 + r3] = s;
    }
}

// ---- P1: streaming Weff build + x->bf16 cast (one launch) -------------------
// Blocks [0,512): Weff[o][d0..d0+7] = bf16(W + 16 * M[d] . NT[o]); e=blk*256+tid,
//   o = e>>7, d0 = (e&127)*8.  Blocks [512, 512+8192): cast 2048 elems each.
__global__ __launch_bounds__(256) void weff_cast_kernel(
    const float* __restrict__ X, const float* __restrict__ W,
    const float* __restrict__ Mws, const float* __restrict__ NTws,
    bf16* __restrict__ Weff, bf16* __restrict__ Xb)
{
    const int tid = threadIdx.x;
    if (blockIdx.x >= 512) {
        size_t i = ((size_t)(blockIdx.x - 512) * 256 + tid) * 8;
        f32x4 a = *(const f32x4*)&X[i];
        f32x4 b = *(const f32x4*)&X[i + 4];
        bf16x8 v;
        v[0] = (bf16)a[0]; v[1] = (bf16)a[1]; v[2] = (bf16)a[2]; v[3] = (bf16)a[3];
        v[4] = (bf16)b[0]; v[5] = (bf16)b[1]; v[6] = (bf16)b[2]; v[7] = (bf16)b[3];
        *(bf16x8*)&Xb[i] = v;
        return;
    }
    int e  = blockIdx.x * 256 + tid;
    int o  = e >> 7;
    int d0 = (e & 127) * 8;
    f32x4 nt0 = *(const f32x4*)&NTws[o * 8];
    f32x4 nt1 = *(const f32x4*)&NTws[o * 8 + 4];
    f32x4 w0 = *(const f32x4*)&W[(size_t)o * D_DIM + d0];
    f32x4 w1 = *(const f32x4*)&W[(size_t)o * D_DIM + d0 + 4];
    bf16x8 res;
    for (int k = 0; k < 8; ++k) {
        f32x4 m0 = *(const f32x4*)&Mws[(d0 + k) * 8];
        f32x4 m1 = *(const f32x4*)&Mws[(d0 + k) * 8 + 4];
        float acc = m0[0]*nt0[0] + m0[1]*nt0[1] + m0[2]*nt0[2] + m0[3]*nt0[3]
                  + m1[0]*nt1[0] + m1[1]*nt1[1] + m1[2]*nt1[2] + m1[3]*nt1[3];
        float w = (k < 4) ? w0[k] : w1[k - 4];
        res[k] = (bf16)(w + ALPHA_F * acc);
    }
    *(bf16x8*)&Weff[(size_t)o * D_DIM + d0] = res;
}

// ---- GEMM v3: 16384x1024x1024 bf16, 256x256 tile, 32x32x16 MFMA, BK=32 ------
// 8 waves 2Mx4N, per-wave 128x64 (4x2 frags of 32x32) -> LDS read/flop -25%.
// LDS rows 64B = 4 chunks of 16B; stored chunk = logical ^ ((row>>1)&3):
// per 8-lane b128 phase, even rows cover banks 0-15 (4 distinct chunks), odd
// rows banks 16-31 -> conflict-free. 4 buffers x 32KB = 128KB, stage 3 ahead,
// steady wait vmcnt(8) (tile t+1 landed, t+2/t+3 stay in flight).
#define TBM 256
#define TBN 256
#define TBK 32
#define ABYT (TBM * TBK * 2)     // 16 KB
#define BBYT (TBN * TBK * 2)     // 16 KB
#define BUF2 (ABYT + BBYT)       // 32 KB
#define NB2  4
#define NT2  (D_DIM / TBK)       // 32

__global__ __launch_bounds__(512, 2) void gemm_pipe2_kernel(
    const bf16* __restrict__ Xb,
    const bf16* __restrict__ Weff,
    const float* __restrict__ bias,
    float* __restrict__ Out)
{
    extern __shared__ __attribute__((aligned(16))) char smem[];

    const int tid  = threadIdx.x;
    const int wave = tid >> 6, lane = tid & 63;

    // XCD swizzle: 256 blocks, 8 XCDs -> each XCD: 8 mtiles x 4 ntiles.
    const int bid   = blockIdx.x;
    const int slot  = (bid & 7) * 32 + (bid >> 3);
    const int mtile = slot >> 2;          // [0,64)
    const int ntile = slot & 3;           // [0,4)

    const int wr = wave >> 2, wc = wave & 3;       // 2M x 4N
    const int l31 = lane & 31, half = lane >> 5;
    const int swz = (l31 >> 1) & 3;                // read-side chunk XOR

    // Staging: lane l -> row set*128 + wave*16 + (l>>2), stored chunk l&3,
    // so global chunk = (l&3) ^ ((row>>1)&3) = (l&3) ^ ((l>>3)&3).
    const int srow   = wave * 16 + (lane >> 2);
    const int lchunk = (lane & 3) ^ ((lane >> 3) & 3);
    const bf16* asrc = Xb   + (size_t)(mtile * TBM + srow) * D_DIM + lchunk * 8;
    const bf16* bsrc = Weff + (size_t)(ntile * TBN + srow) * D_DIM + lchunk * 8;
    const int woff = wave * 1024;

    auto STAGE = [&](int bo, int t) {
        const bf16* ap = asrc + t * TBK;
        const bf16* bp = bsrc + t * TBK;
        __builtin_amdgcn_global_load_lds(GPTR(ap),
                                         SPTR(smem + bo + woff), 16, 0, 0);
        __builtin_amdgcn_global_load_lds(GPTR(ap + (size_t)128 * D_DIM),
                                         SPTR(smem + bo + 8192 + woff), 16, 0, 0);
        __builtin_amdgcn_global_load_lds(GPTR(bp),
                                         SPTR(smem + bo + ABYT + woff), 16, 0, 0);
        __builtin_amdgcn_global_load_lds(GPTR(bp + (size_t)128 * D_DIM),
                                         SPTR(smem + bo + ABYT + 8192 + woff), 16, 0, 0);
    };

    f32x16 acc[4][2];
#pragma unroll
    for (int i = 0; i < 4; ++i)
#pragma unroll
        for (int j = 0; j < 2; ++j)
#pragma unroll
            for (int r = 0; r < 16; ++r) acc[i][j][r] = 0.f;

    auto COMPUTE = [&](int bo) {
        const char* Ab = smem + bo;
        const char* Bb = smem + bo + ABYT;
#pragma unroll
        for (int kk = 0; kk < 2; ++kk) {
            const int sc16 = (((kk * 2 + half) ^ swz) * 16);
            bf16x8 af[4], bfr[2];
#pragma unroll
            for (int i = 0; i < 4; ++i)
                af[i] = *(const bf16x8*)(Ab + (wr * 128 + i * 32 + l31) * 64 + sc16);
#pragma unroll
            for (int j = 0; j < 2; ++j)
                bfr[j] = *(const bf16x8*)(Bb + (wc * 64 + j * 32 + l31) * 64 + sc16);
            __builtin_amdgcn_s_setprio(1);
#pragma unroll
            for (int i = 0; i < 4; ++i)
#pragma unroll
                for (int j = 0; j < 2; ++j)
                    acc[i][j] = __builtin_amdgcn_mfma_f32_32x32x16_bf16(
                        af[i], bfr[j], acc[i][j], 0, 0, 0);
            __builtin_amdgcn_s_setprio(0);
        }
    };

    // Prologue: stage tiles 0..2; wait tile 0 (12 outstanding, oldest 4 done).
    STAGE(0, 0);
    STAGE(BUF2, 1);
    STAGE(2 * BUF2, 2);
    asm volatile("s_waitcnt vmcnt(8)" ::: "memory");
    __builtin_amdgcn_s_barrier();
    __builtin_amdgcn_sched_barrier(0);

    int bo = 0;
    for (int t = 0; t < NT2 - 3; ++t) {
        int bs = bo + 3 * BUF2; if (bs >= NB2 * BUF2) bs -= NB2 * BUF2;
        STAGE(bs, t + 3);
        COMPUTE(bo);
        asm volatile("s_waitcnt vmcnt(8) lgkmcnt(0)" ::: "memory");
        __builtin_amdgcn_s_barrier();
        __builtin_amdgcn_sched_barrier(0);
        bo += BUF2; if (bo == NB2 * BUF2) bo = 0;
    }
    // Tail: tiles NT2-3, NT2-2, NT2-1 (nothing left to stage).
    COMPUTE(bo);
    asm volatile("s_waitcnt vmcnt(4) lgkmcnt(0)" ::: "memory");
    __builtin_amdgcn_s_barrier();
    __builtin_amdgcn_sched_barrier(0);
    bo += BUF2; if (bo == NB2 * BUF2) bo = 0;
    COMPUTE(bo);
    asm volatile("s_waitcnt vmcnt(0) lgkmcnt(0)" ::: "memory");
    __builtin_amdgcn_s_barrier();
    __builtin_amdgcn_sched_barrier(0);
    bo += BUF2; if (bo == NB2 * BUF2) bo = 0;
    COMPUTE(bo);

    // Epilogue: 32x32 C/D layout col = lane&31, row = (r&3) + 8*(r>>2) + 4*half
    float bj[2];
#pragma unroll
    for (int j = 0; j < 2; ++j)
        bj[j] = bias[ntile * TBN + wc * 64 + j * 32 + l31];
#pragma unroll
    for (int i = 0; i < 4; ++i) {
        int rbase = mtile * TBM + wr * 128 + i * 32 + 4 * half;
#pragma unroll
        for (int j = 0; j < 2; ++j) {
            int col = ntile * TBN + wc * 64 + j * 32 + l31;
#pragma unroll
            for (int r = 0; r < 16; ++r) {
                int row = rbase + (r & 3) + 8 * (r >> 2);
                Out[(size_t)row * D_DIM + col] = acc[i][j][r] + bj[j];
            }
        }
    }
}

// ---- Fallback GEMM (proven 128x128, BK=64) — used if dyn-LDS attr fails -----
__global__ __launch_bounds__(256) void gemm_bb_kernel(
    const bf16* __restrict__ Xb,
    const bf16* __restrict__ Weff,
    const float* __restrict__ bias,
    float* __restrict__ Out)
{
    __shared__ __align__(16) bf16 As[BM][64];
    __shared__ __align__(16) bf16 Bs[BN][64];

    const int tid  = threadIdx.x;
    const int wave = tid >> 6, lane = tid & 63;
    const int mtile = blockIdx.x, ntile = blockIdx.y;
    const int wr = wave >> 1, wc = wave & 1;
    const int l15 = lane & 15, quad = lane >> 4;

    const int srow = wave * 32 + (lane >> 3);
    const int gchunk = (lane & 7) ^ (lane >> 3);
    const bf16* asrc = Xb   + (size_t)(mtile * BM + srow) * D_DIM + gchunk * 8;
    const bf16* bsrc = Weff + (size_t)(ntile * BN + srow) * D_DIM + gchunk * 8;
    char* abase = (char*)&As[0][0] + wave * 4096;
    char* bbase = (char*)&Bs[0][0] + wave * 4096;

    const int rsw = l15 & 7;

    f32x4 acc[4][4];
    for (int i = 0; i < 4; ++i)
        for (int j = 0; j < 4; ++j)
            for (int r = 0; r < 4; ++r) acc[i][j][r] = 0.f;

    for (int kt = 0; kt < D_DIM / 64; ++kt) {
        const int ko = kt * 64;
        for (int j = 0; j < 4; ++j) {
            __builtin_amdgcn_global_load_lds(GPTR(asrc + (size_t)j * 8 * D_DIM + ko),
                                             SPTR(abase + j * 1024), 16, 0, 0);
            __builtin_amdgcn_global_load_lds(GPTR(bsrc + (size_t)j * 8 * D_DIM + ko),
                                             SPTR(bbase + j * 1024), 16, 0, 0);
        }
        __syncthreads();
        for (int kk = 0; kk < 2; ++kk) {
            const int lc = kk * 4 + quad;
            const int sc = (lc ^ rsw) * 8;
            bf16x8 af[4], bfr[4];
            for (int i = 0; i < 4; ++i)
                af[i] = *(const bf16x8*)&As[wr * 64 + i * 16 + l15][sc];
            for (int j = 0; j < 4; ++j)
                bfr[j] = *(const bf16x8*)&Bs[wc * 64 + j * 16 + l15][sc];
            for (int i = 0; i < 4; ++i)
                for (int j = 0; j < 4; ++j)
                    acc[i][j] = __builtin_amdgcn_mfma_f32_16x16x32_bf16(
                        af[i], bfr[j], acc[i][j], 0, 0, 0);
        }
        __syncthreads();
    }

    float bj[4];
    for (int j = 0; j < 4; ++j)
        bj[j] = bias[ntile * BN + wc * 64 + j * 16 + l15];
    for (int i = 0; i < 4; ++i) {
        int row0 = mtile * BM + wr * 64 + i * 16 + quad * 4;
        for (int r = 0; r < 4; ++r) {
            float* orow = Out + (size_t)(row0 + r) * D_DIM + ntile * BN + wc * 64 + l15;
            for (int j = 0; j < 4; ++j)
                orow[j * 16] = acc[i][j][r] + bj[j];
        }
    }
}

// ---- Fallback GEMM (fp32 A staged via VALU convert) — used if ws too small --
__global__ __launch_bounds__(256) void gemm_bias_kernel(
    const float* __restrict__ X,
    const bf16* __restrict__ Weff,
    const float* __restrict__ bias,
    float* __restrict__ Out)
{
    __shared__ __align__(16) bf16 As[BM][32];
    __shared__ __align__(16) bf16 Bs[BN][32];

    const int tid  = threadIdx.x;
    const int wave = tid >> 6, lane = tid & 63;
    const int mtile = blockIdx.x, ntile = blockIdx.y;
    const int wr = wave >> 1, wc = wave & 1;
    const int l15 = lane & 15, quad = lane >> 4;

    const int ar = tid >> 1, ah = tid & 1;
    const float* xsrc = X + (size_t)(mtile * BM + ar) * D_DIM + ah * 16;
    bf16* adst = &As[ar][ah * 16];

    const bf16* bsrc0 = Weff + (size_t)(ntile * BN + wave * 32 + (lane >> 2)) * D_DIM
                        + (lane & 3) * 8;
    const bf16* bsrc1 = bsrc0 + 16 * D_DIM;
    char* bbase = (char*)&Bs[0][0];
    void* bdst0 = bbase + wave * 2048;
    void* bdst1 = bbase + wave * 2048 + 1024;

    f32x4 acc[4][4];
    for (int i = 0; i < 4; ++i)
        for (int j = 0; j < 4; ++j)
            for (int r = 0; r < 4; ++r) acc[i][j][r] = 0.f;

    for (int kt = 0; kt < D_DIM / 32; ++kt) {
        __builtin_amdgcn_global_load_lds(GPTR(bsrc0 + kt * 32), SPTR(bdst0), 16, 0, 0);
        __builtin_amdgcn_global_load_lds(GPTR(bsrc1 + kt * 32), SPTR(bdst1), 16, 0, 0);

        const f32x4* xp = (const f32x4*)(xsrc + kt * 32);
        f32x4 f0 = xp[0], f1 = xp[1], f2 = xp[2], f3 = xp[3];
        bf16x8 p0, p1;
        p0[0] = (bf16)f0[0]; p0[1] = (bf16)f0[1]; p0[2] = (bf16)f0[2]; p0[3] = (bf16)f0[3];
        p0[4] = (bf16)f1[0]; p0[5] = (bf16)f1[1]; p0[6] = (bf16)f1[2]; p0[7] = (bf16)f1[3];
        p1[0] = (bf16)f2[0]; p1[1] = (bf16)f2[1]; p1[2] = (bf16)f2[2]; p1[3] = (bf16)f2[3];
        p1[4] = (bf16)f3[0]; p1[5] = (bf16)f3[1]; p1[6] = (bf16)f3[2]; p1[7] = (bf16)f3[3];
        *(bf16x8*)adst = p0;
        *(bf16x8*)(adst + 8) = p1;

        __syncthreads();

        bf16x8 af[4], bfr[4];
        for (int i = 0; i < 4; ++i)
            af[i] = *(const bf16x8*)&As[wr * 64 + i * 16 + l15][quad * 8];
        for (int j = 0; j < 4; ++j)
            bfr[j] = *(const bf16x8*)&Bs[wc * 64 + j * 16 + l15][quad * 8];
        for (int i = 0; i < 4; ++i)
            for (int j = 0; j < 4; ++j)
                acc[i][j] = __builtin_amdgcn_mfma_f32_16x16x32_bf16(
                    af[i], bfr[j], acc[i][j], 0, 0, 0);

        __syncthreads();
    }

    float bj[4];
    for (int j = 0; j < 4; ++j)
        bj[j] = bias[ntile * BN + wc * 64 + j * 16 + l15];
    for (int i = 0; i < 4; ++i) {
        int row0 = mtile * BM + wr * 64 + i * 16 + quad * 4;
        for (int r = 0; r < 4; ++r) {
            float* orow = Out + (size_t)(row0 + r) * D_DIM + ntile * BN + wc * 64 + l15;
            for (int j = 0; j < 4; ++j)
                orow[j * 16] = acc[i][j][r] + bj[j];
        }
    }
}

// Standalone Weff builder for tiny-ws fallback path
__global__ __launch_bounds__(256) void build_weff_fused_kernel(
    const float* __restrict__ W,
    const float* __restrict__ c0, const float* __restrict__ c1,
    const float* __restrict__ c2, const float* __restrict__ c3,
    const float* __restrict__ c4, const float* __restrict__ c5,
    bf16* __restrict__ Weff)
{
    __shared__ float t2[1024];
    __shared__ float Msh[8192];
    const int tid = threadIdx.x;
    const int o = blockIdx.x;

    for (int e = tid; e < 1024; e += 256) {
        int p2 = e & 7, i2i1 = e >> 3;
        int i1 = i2i1 & 7, i2 = i2i1 >> 3;
        float s = 0.f;
        for (int p1 = 0; p1 < 8; ++p1)
            s += c0[i1 * 8 + p1] * c1[p1 * 128 + i2 * 8 + p2];
        t2[e] = s;
    }
    __syncthreads();
    for (int e = tid; e < 8192; e += 256) {
        int p3 = e & 7, d = e >> 3;
        int i1 = d & 7, i2 = (d >> 3) & 15, i3 = d >> 7;
        float s = 0.f;
        for (int p2 = 0; p2 < 8; ++p2)
            s += t2[(i2 * 8 + i1) * 8 + p2] * c2[p2 * 64 + i3 * 8 + p3];
        Msh[e] = s;
    }
    int n1 = o >> 7, nn = o & 127, n2 = nn >> 3, n3 = nn & 7;
    float v[8];
    for (int p4 = 0; p4 < 8; ++p4) {
        float s = 0.f;
        for (int p5 = 0; p5 < 8; ++p5)
            s += c4[p4 * 128 + n2 * 8 + p5] * c5[p5 * 8 + n3];
        v[p4] = s;
    }
    float ncol[8];
    for (int r3 = 0; r3 < 8; ++r3) {
        float s = 0.f;
        for (int p4 = 0; p4 < 8; ++p4)
            s += c3[r3 * 64 + n1 * 8 + p4] * v[p4];
        ncol[r3] = s;
    }
    __syncthreads();

    int d0 = tid * 4;
    f32x4 w = *(const f32x4*)&W[o * D_DIM + d0];
    bf16x4 res;
    for (int k = 0; k < 4; ++k) {
        float acc = 0.f;
        for (int r = 0; r < 8; ++r)
            acc += Msh[(d0 + k) * 8 + r] * ncol[r];
        res[k] = (bf16)(w[k] + ALPHA_F * acc);
    }
    *(bf16x4*)&Weff[o * D_DIM + d0] = res;
}

extern "C" void kernel_launch(void* const* d_in, const int* in_sizes, int n_in,
                              void* d_out, int out_size, void* d_ws, size_t ws_size,
                              hipStream_t stream) {
    const float* x  = (const float*)d_in[0];
    const float* W  = (const float*)d_in[1];
    const float* b  = (const float*)d_in[2];
    const float* c0 = (const float*)d_in[3];
    const float* c1 = (const float*)d_in[4];
    const float* c2 = (const float*)d_in[5];
    const float* c3 = (const float*)d_in[6];
    const float* c4 = (const float*)d_in[7];
    const float* c5 = (const float*)d_in[8];
    float* out = (float*)d_out;

    // Workspace: Weff bf16 2MB @0 | M 32KB + NT 32KB @2MB | Xb 32MB @4MB
    char* ws = (char*)d_ws;
    bf16*  Weff = (bf16*)ws;
    float* Mws  = (float*)(ws + 2u * 1024u * 1024u);
    float* NTws = Mws + 8192;
    bf16*  Xb   = (bf16*)(ws + 4u * 1024u * 1024u);
    const size_t need = 4u * 1024u * 1024u + (size_t)BS_ROWS * D_DIM * 2u;

    // One-time: raise dynamic-LDS cap for the pipelined GEMM (128 KB).
    static int smem_ok = -1;
    if (smem_ok < 0) {
        hipError_t e = hipFuncSetAttribute((const void*)gemm_pipe2_kernel,
                                           hipFuncAttributeMaxDynamicSharedMemorySize,
                                           NB2 * BUF2);
        smem_ok = (e == hipSuccess) ? 1 : 0;
    }

    if (ws_size >= need) {
        make_mn_kernel<<<1, 256, 0, stream>>>(c0, c1, c2, c3, c4, c5, Mws, NTws);
        weff_cast_kernel<<<512 + 8192, 256, 0, stream>>>(x, W, Mws, NTws, Weff, Xb);
        if (smem_ok) {
            gemm_pipe2_kernel<<<dim3(256), 512, NB2 * BUF2, stream>>>(Xb, Weff, b, out);
        } else {
            dim3 grid(BS_ROWS / BM, D_DIM / BN);
            gemm_bb_kernel<<<grid, 256, 0, stream>>>(Xb, Weff, b, out);
        }
    } else {
        build_weff_fused_kernel<<<D_DIM, 256, 0, stream>>>(W, c0, c1, c2, c3, c4, c5, Weff);
        dim3 grid(BS_ROWS / BM, D_DIM / BN);
        gemm_bias_kernel<<<grid, 256, 0, stream>>>(x, Weff, b, out);
    }
}

// Round 3
// 163.914 us; speedup vs baseline: 1.1261x; 1.1261x over previous
//
#include <hip/hip_runtime.h>
#include <hip/hip_bf16.h>

// out = x @ (W + 16*(M@N))^T + b  where M(1024x8), N(8x1024) are folded TT cores.
// v4: GEMM = 256x256 tile, BK=64 (proven 128B-row LDS geometry, chunk^(row&7)
// swizzle = 0 bank conflicts), 8 waves 2Mx4N, per-wave 128x64 via 32x32x16 MFMA,
// 2-buffer ping-pong with counted vmcnt(8), grid=256 blocks = 1/CU, XCD swizzle.
// Prep: make_mn (64 blocks) -> weff_cast (streaming Weff build + x cast).

#define D_DIM 1024
#define BS_ROWS 16384
#define ALPHA_F 16.0f
#define BM 128
#define BN 128

using bf16   = __bf16;
using bf16x8 = __attribute__((ext_vector_type(8))) __bf16;
using bf16x4 = __attribute__((ext_vector_type(4))) __bf16;
using f32x4  = __attribute__((ext_vector_type(4))) float;
using f32x16 = __attribute__((ext_vector_type(16))) float;

#define GPTR(p) (const __attribute__((address_space(1))) void*)(p)
#define SPTR(p) (__attribute__((address_space(3))) void*)(p)

// ---- P0: compute M[1024][8] and NT[1024][8] (64 blocks) ---------------------
// Blocks [0,32): M slice.  Blocks [32,64): NT slice.  256 entries per block.
__global__ __launch_bounds__(256) void make_mn_kernel(
    const float* __restrict__ c0, const float* __restrict__ c1,
    const float* __restrict__ c2, const float* __restrict__ c3,
    const float* __restrict__ c4, const float* __restrict__ c5,
    float* __restrict__ Mws, float* __restrict__ NTws)
{
    __shared__ float sh[128 * 9];   // padded stride 9
    const int tid = threadIdx.x;

    if (blockIdx.x < 32) {
        // t2[(i2*8+i1)][p2] = sum_p1 c0[0,i1,p1]*c1[p1,i2,p2]
        for (int e = tid; e < 1024; e += 256) {
            int p2 = e & 7, i2i1 = e >> 3;
            int i1 = i2i1 & 7, i2 = i2i1 >> 3;
            float s = 0.f;
            for (int p1 = 0; p1 < 8; ++p1)
                s += c0[i1 * 8 + p1] * c1[p1 * 128 + i2 * 8 + p2];
            sh[i2i1 * 9 + p2] = s;
        }
        __syncthreads();
        // M[d][p3] = sum_p2 t2[i2*8+i1][p2]*c2[p2,i3,p3], d = i3*128+i2*8+i1
        int e = blockIdx.x * 256 + tid;       // [0,8192)
        int p3 = e & 7, d = e >> 3;
        int i1 = d & 7, i2 = (d >> 3) & 15, i3 = d >> 7;
        float s = 0.f;
        for (int p2 = 0; p2 < 8; ++p2)
            s += sh[(i2 * 8 + i1) * 9 + p2] * c2[p2 * 64 + i3 * 8 + p3];
        Mws[e] = s;
    } else {
        // vt[(n2*8+n3)][p4] = sum_p5 c4[p4,n2,p5]*c5[p5,n3]
        for (int e = tid; e < 1024; e += 256) {
            int p4 = e & 7, nn = e >> 3;
            int n2 = nn >> 3, n3 = nn & 7;
            float s = 0.f;
            for (int p5 = 0; p5 < 8; ++p5)
                s += c4[p4 * 128 + n2 * 8 + p5] * c5[p5 * 8 + n3];
            sh[nn * 9 + p4] = s;
        }
        __syncthreads();
        // NT[o][r3] = sum_p4 c3[r3,n1,p4]*vt[n2n3][p4], o = n1*128+n2*8+n3
        int e = (blockIdx.x - 32) * 256 + tid;
        int r3 = e & 7, o = e >> 3;
        int n1 = o >> 7, nn = o & 127;
        float s = 0.f;
        for (int p4 = 0; p4 < 8; ++p4)
            s += c3[r3 * 64 + n1 * 8 + p4] * sh[nn * 9 + p4];
        NTws[o * 8 + r3] = s;
    }
}

// ---- P1: streaming Weff build + x->bf16 cast (one launch) -------------------
__global__ __launch_bounds__(256) void weff_cast_kernel(
    const float* __restrict__ X, const float* __restrict__ W,
    const float* __restrict__ Mws, const float* __restrict__ NTws,
    bf16* __restrict__ Weff, bf16* __restrict__ Xb)
{
    const int tid = threadIdx.x;
    if (blockIdx.x >= 512) {
        size_t i = ((size_t)(blockIdx.x - 512) * 256 + tid) * 8;
        f32x4 a = *(const f32x4*)&X[i];
        f32x4 b = *(const f32x4*)&X[i + 4];
        bf16x8 v;
        v[0] = (bf16)a[0]; v[1] = (bf16)a[1]; v[2] = (bf16)a[2]; v[3] = (bf16)a[3];
        v[4] = (bf16)b[0]; v[5] = (bf16)b[1]; v[6] = (bf16)b[2]; v[7] = (bf16)b[3];
        *(bf16x8*)&Xb[i] = v;
        return;
    }
    int e  = blockIdx.x * 256 + tid;
    int o  = e >> 7;
    int d0 = (e & 127) * 8;
    f32x4 nt0 = *(const f32x4*)&NTws[o * 8];
    f32x4 nt1 = *(const f32x4*)&NTws[o * 8 + 4];
    f32x4 w0 = *(const f32x4*)&W[(size_t)o * D_DIM + d0];
    f32x4 w1 = *(const f32x4*)&W[(size_t)o * D_DIM + d0 + 4];
    bf16x8 res;
    for (int k = 0; k < 8; ++k) {
        f32x4 m0 = *(const f32x4*)&Mws[(d0 + k) * 8];
        f32x4 m1 = *(const f32x4*)&Mws[(d0 + k) * 8 + 4];
        float acc = m0[0]*nt0[0] + m0[1]*nt0[1] + m0[2]*nt0[2] + m0[3]*nt0[3]
                  + m1[0]*nt1[0] + m1[1]*nt1[1] + m1[2]*nt1[2] + m1[3]*nt1[3];
        float w = (k < 4) ? w0[k] : w1[k - 4];
        res[k] = (bf16)(w + ALPHA_F * acc);
    }
    *(bf16x8*)&Weff[(size_t)o * D_DIM + d0] = res;
}

// ---- GEMM v4: 16384x1024x1024 bf16, 256x256 tile, 32x32x16 MFMA, BK=64 ------
// LDS rows 128B = 8 x 16B chunks; stored chunk = logical ^ (row&7) (PROVEN:
// 0 conflicts in rounds 0/1). 8 waves 2Mx4N, wave-tile 128x64 (4x2 frags of
// 32x32) -> 43.7 FLOP per LDS byte. 2 buffers x 64KB ping-pong; per tile:
// COMPUTE(t) -> barrier -> STAGE(t+2 into freed buf) -> vmcnt(8) (t+1 landed,
// t+2's 8 loads stay in flight) -> barrier. Grid 256 = 1 block/CU, one round.
#define TBM 256
#define TBN 256
#define TBK 64
#define ABYT (TBM * TBK * 2)     // 32 KB
#define BBYT (TBN * TBK * 2)     // 32 KB
#define BUF4 (ABYT + BBYT)       // 64 KB
#define NT4  (D_DIM / TBK)       // 16

__global__ __launch_bounds__(512, 2) void gemm_pipe4_kernel(
    const bf16* __restrict__ Xb,
    const bf16* __restrict__ Weff,
    const float* __restrict__ bias,
    float* __restrict__ Out)
{
    extern __shared__ __attribute__((aligned(16))) char smem[];

    const int tid  = threadIdx.x;
    const int wave = tid >> 6, lane = tid & 63;

    // XCD swizzle: 256 blocks, 8 XCDs -> each XCD: 8 mtiles x 4 ntiles.
    const int bid   = blockIdx.x;
    const int slot  = (bid & 7) * 32 + (bid >> 3);
    const int mtile = slot >> 2;          // [0,64)
    const int ntile = slot & 3;           // [0,4)

    const int wr = wave >> 2, wc = wave & 3;       // 2M x 4N
    const int l31 = lane & 31, half = lane >> 5;
    const int rsw = l31 & 7;                       // read swizzle = row&7

    // Staging (proven pattern): wave w, issue j covers rows w*32+j*8+(l>>3);
    // stored chunk = l&7, so global chunk = (l&7)^(l>>3). LDS dst linear.
    const int srow   = wave * 32 + (lane >> 3);
    const int gchunk = (lane & 7) ^ (lane >> 3);
    const bf16* asrc = Xb   + (size_t)(mtile * TBM + srow) * D_DIM + gchunk * 8;
    const bf16* bsrc = Weff + (size_t)(ntile * TBN + srow) * D_DIM + gchunk * 8;
    const int woff = wave * 4096;

    auto STAGE = [&](int bo, int t) {
        const bf16* ap = asrc + t * TBK;
        const bf16* bp = bsrc + t * TBK;
#pragma unroll
        for (int j = 0; j < 4; ++j)
            __builtin_amdgcn_global_load_lds(GPTR(ap + (size_t)j * 8 * D_DIM),
                                             SPTR(smem + bo + woff + j * 1024), 16, 0, 0);
#pragma unroll
        for (int j = 0; j < 4; ++j)
            __builtin_amdgcn_global_load_lds(GPTR(bp + (size_t)j * 8 * D_DIM),
                                             SPTR(smem + bo + ABYT + woff + j * 1024), 16, 0, 0);
    };

    f32x16 acc[4][2];
#pragma unroll
    for (int i = 0; i < 4; ++i)
#pragma unroll
        for (int j = 0; j < 2; ++j)
#pragma unroll
            for (int r = 0; r < 16; ++r) acc[i][j][r] = 0.f;

    auto COMPUTE = [&](int bo) {
        const char* Ab = smem + bo;
        const char* Bb = smem + bo + ABYT;
#pragma unroll
        for (int kk = 0; kk < 4; ++kk) {
            const int sb = (((kk * 2 + half) ^ rsw) * 16);  // swizzled chunk (bytes)
            bf16x8 af[4], bfr[2];
#pragma unroll
            for (int i = 0; i < 4; ++i)
                af[i] = *(const bf16x8*)(Ab + (wr * 128 + i * 32 + l31) * 128 + sb);
#pragma unroll
            for (int j = 0; j < 2; ++j)
                bfr[j] = *(const bf16x8*)(Bb + (wc * 64 + j * 32 + l31) * 128 + sb);
            __builtin_amdgcn_s_setprio(1);
#pragma unroll
            for (int i = 0; i < 4; ++i)
#pragma unroll
                for (int j = 0; j < 2; ++j)
                    acc[i][j] = __builtin_amdgcn_mfma_f32_32x32x16_bf16(
                        af[i], bfr[j], acc[i][j], 0, 0, 0);
            __builtin_amdgcn_s_setprio(0);
        }
    };

    // Prologue: stage tiles 0,1 (8 issues each); wait tile 0; barrier.
    STAGE(0, 0);
    STAGE(BUF4, 1);
    asm volatile("s_waitcnt vmcnt(8)" ::: "memory");
    __builtin_amdgcn_s_barrier();
    __builtin_amdgcn_sched_barrier(0);

    for (int t = 0; t < NT4 - 2; ++t) {
        const int bo = (t & 1) * BUF4;
        COMPUTE(bo);
        asm volatile("s_waitcnt lgkmcnt(0)" ::: "memory");
        __builtin_amdgcn_s_barrier();           // all waves done reading buf
        __builtin_amdgcn_sched_barrier(0);
        STAGE(bo, t + 2);                       // overwrite freed buf
        // outstanding = t+1's 8 + t+2's 8; wait until t+1 landed.
        asm volatile("s_waitcnt vmcnt(8)" ::: "memory");
        __builtin_amdgcn_s_barrier();
        __builtin_amdgcn_sched_barrier(0);
    }
    // Tile NT4-2 (nothing to stage); drain for last tile.
    COMPUTE(((NT4 - 2) & 1) * BUF4);
    asm volatile("s_waitcnt lgkmcnt(0)" ::: "memory");
    __builtin_amdgcn_s_barrier();
    __builtin_amdgcn_sched_barrier(0);
    asm volatile("s_waitcnt vmcnt(0)" ::: "memory");
    __builtin_amdgcn_s_barrier();
    __builtin_amdgcn_sched_barrier(0);
    COMPUTE(((NT4 - 1) & 1) * BUF4);

    // Epilogue (verified in v3): col = lane&31, row = (r&3)+8*(r>>2)+4*half
    float bj[2];
#pragma unroll
    for (int j = 0; j < 2; ++j)
        bj[j] = bias[ntile * TBN + wc * 64 + j * 32 + l31];
#pragma unroll
    for (int i = 0; i < 4; ++i) {
        int rbase = mtile * TBM + wr * 128 + i * 32 + 4 * half;
#pragma unroll
        for (int j = 0; j < 2; ++j) {
            int col = ntile * TBN + wc * 64 + j * 32 + l31;
#pragma unroll
            for (int r = 0; r < 16; ++r) {
                int row = rbase + (r & 3) + 8 * (r >> 2);
                Out[(size_t)row * D_DIM + col] = acc[i][j][r] + bj[j];
            }
        }
    }
}

// ---- Fallback GEMM (proven 128x128, BK=64) — used if dyn-LDS attr fails -----
__global__ __launch_bounds__(256) void gemm_bb_kernel(
    const bf16* __restrict__ Xb,
    const bf16* __restrict__ Weff,
    const float* __restrict__ bias,
    float* __restrict__ Out)
{
    __shared__ __align__(16) bf16 As[BM][64];
    __shared__ __align__(16) bf16 Bs[BN][64];

    const int tid  = threadIdx.x;
    const int wave = tid >> 6, lane = tid & 63;
    const int mtile = blockIdx.x, ntile = blockIdx.y;
    const int wr = wave >> 1, wc = wave & 1;
    const int l15 = lane & 15, quad = lane >> 4;

    const int srow = wave * 32 + (lane >> 3);
    const int gchunk = (lane & 7) ^ (lane >> 3);
    const bf16* asrc = Xb   + (size_t)(mtile * BM + srow) * D_DIM + gchunk * 8;
    const bf16* bsrc = Weff + (size_t)(ntile * BN + srow) * D_DIM + gchunk * 8;
    char* abase = (char*)&As[0][0] + wave * 4096;
    char* bbase = (char*)&Bs[0][0] + wave * 4096;

    const int rsw = l15 & 7;

    f32x4 acc[4][4];
    for (int i = 0; i < 4; ++i)
        for (int j = 0; j < 4; ++j)
            for (int r = 0; r < 4; ++r) acc[i][j][r] = 0.f;

    for (int kt = 0; kt < D_DIM / 64; ++kt) {
        const int ko = kt * 64;
        for (int j = 0; j < 4; ++j) {
            __builtin_amdgcn_global_load_lds(GPTR(asrc + (size_t)j * 8 * D_DIM + ko),
                                             SPTR(abase + j * 1024), 16, 0, 0);
            __builtin_amdgcn_global_load_lds(GPTR(bsrc + (size_t)j * 8 * D_DIM + ko),
                                             SPTR(bbase + j * 1024), 16, 0, 0);
        }
        __syncthreads();
        for (int kk = 0; kk < 2; ++kk) {
            const int lc = kk * 4 + quad;
            const int sc = (lc ^ rsw) * 8;
            bf16x8 af[4], bfr[4];
            for (int i = 0; i < 4; ++i)
                af[i] = *(const bf16x8*)&As[wr * 64 + i * 16 + l15][sc];
            for (int j = 0; j < 4; ++j)
                bfr[j] = *(const bf16x8*)&Bs[wc * 64 + j * 16 + l15][sc];
            for (int i = 0; i < 4; ++i)
                for (int j = 0; j < 4; ++j)
                    acc[i][j] = __builtin_amdgcn_mfma_f32_16x16x32_bf16(
                        af[i], bfr[j], acc[i][j], 0, 0, 0);
        }
        __syncthreads();
    }

    float bj[4];
    for (int j = 0; j < 4; ++j)
        bj[j] = bias[ntile * BN + wc * 64 + j * 16 + l15];
    for (int i = 0; i < 4; ++i) {
        int row0 = mtile * BM + wr * 64 + i * 16 + quad * 4;
        for (int r = 0; r < 4; ++r) {
            float* orow = Out + (size_t)(row0 + r) * D_DIM + ntile * BN + wc * 64 + l15;
            for (int j = 0; j < 4; ++j)
                orow[j * 16] = acc[i][j][r] + bj[j];
        }
    }
}

// ---- Fallback GEMM (fp32 A staged via VALU convert) — used if ws too small --
__global__ __launch_bounds__(256) void gemm_bias_kernel(
    const float* __restrict__ X,
    const bf16* __restrict__ Weff,
    const float* __restrict__ bias,
    float* __restrict__ Out)
{
    __shared__ __align__(16) bf16 As[BM][32];
    __shared__ __align__(16) bf16 Bs[BN][32];

    const int tid  = threadIdx.x;
    const int wave = tid >> 6, lane = tid & 63;
    const int mtile = blockIdx.x, ntile = blockIdx.y;
    const int wr = wave >> 1, wc = wave & 1;
    const int l15 = lane & 15, quad = lane >> 4;

    const int ar = tid >> 1, ah = tid & 1;
    const float* xsrc = X + (size_t)(mtile * BM + ar) * D_DIM + ah * 16;
    bf16* adst = &As[ar][ah * 16];

    const bf16* bsrc0 = Weff + (size_t)(ntile * BN + wave * 32 + (lane >> 2)) * D_DIM
                        + (lane & 3) * 8;
    const bf16* bsrc1 = bsrc0 + 16 * D_DIM;
    char* bbase = (char*)&Bs[0][0];
    void* bdst0 = bbase + wave * 2048;
    void* bdst1 = bbase + wave * 2048 + 1024;

    f32x4 acc[4][4];
    for (int i = 0; i < 4; ++i)
        for (int j = 0; j < 4; ++j)
            for (int r = 0; r < 4; ++r) acc[i][j][r] = 0.f;

    for (int kt = 0; kt < D_DIM / 32; ++kt) {
        __builtin_amdgcn_global_load_lds(GPTR(bsrc0 + kt * 32), SPTR(bdst0), 16, 0, 0);
        __builtin_amdgcn_global_load_lds(GPTR(bsrc1 + kt * 32), SPTR(bdst1), 16, 0, 0);

        const f32x4* xp = (const f32x4*)(xsrc + kt * 32);
        f32x4 f0 = xp[0], f1 = xp[1], f2 = xp[2], f3 = xp[3];
        bf16x8 p0, p1;
        p0[0] = (bf16)f0[0]; p0[1] = (bf16)f0[1]; p0[2] = (bf16)f0[2]; p0[3] = (bf16)f0[3];
        p0[4] = (bf16)f1[0]; p0[5] = (bf16)f1[1]; p0[6] = (bf16)f1[2]; p0[7] = (bf16)f1[3];
        p1[0] = (bf16)f2[0]; p1[1] = (bf16)f2[1]; p1[2] = (bf16)f2[2]; p1[3] = (bf16)f2[3];
        p1[4] = (bf16)f3[0]; p1[5] = (bf16)f3[1]; p1[6] = (bf16)f3[2]; p1[7] = (bf16)f3[3];
        *(bf16x8*)adst = p0;
        *(bf16x8*)(adst + 8) = p1;

        __syncthreads();

        bf16x8 af[4], bfr[4];
        for (int i = 0; i < 4; ++i)
            af[i] = *(const bf16x8*)&As[wr * 64 + i * 16 + l15][quad * 8];
        for (int j = 0; j < 4; ++j)
            bfr[j] = *(const bf16x8*)&Bs[wc * 64 + j * 16 + l15][quad * 8];
        for (int i = 0; i < 4; ++i)
            for (int j = 0; j < 4; ++j)
                acc[i][j] = __builtin_amdgcn_mfma_f32_16x16x32_bf16(
                    af[i], bfr[j], acc[i][j], 0, 0, 0);

        __syncthreads();
    }

    float bj[4];
    for (int j = 0; j < 4; ++j)
        bj[j] = bias[ntile * BN + wc * 64 + j * 16 + l15];
    for (int i = 0; i < 4; ++i) {
        int row0 = mtile * BM + wr * 64 + i * 16 + quad * 4;
        for (int r = 0; r < 4; ++r) {
            float* orow = Out + (size_t)(row0 + r) * D_DIM + ntile * BN + wc * 64 + l15;
            for (int j = 0; j < 4; ++j)
                orow[j * 16] = acc[i][j][r] + bj[j];
        }
    }
}

// Standalone Weff builder for tiny-ws fallback path
__global__ __launch_bounds__(256) void build_weff_fused_kernel(
    const float* __restrict__ W,
    const float* __restrict__ c0, const float* __restrict__ c1,
    const float* __restrict__ c2, const float* __restrict__ c3,
    const float* __restrict__ c4, const float* __restrict__ c5,
    bf16* __restrict__ Weff)
{
    __shared__ float t2[1024];
    __shared__ float Msh[8192];
    const int tid = threadIdx.x;
    const int o = blockIdx.x;

    for (int e = tid; e < 1024; e += 256) {
        int p2 = e & 7, i2i1 = e >> 3;
        int i1 = i2i1 & 7, i2 = i2i1 >> 3;
        float s = 0.f;
        for (int p1 = 0; p1 < 8; ++p1)
            s += c0[i1 * 8 + p1] * c1[p1 * 128 + i2 * 8 + p2];
        t2[e] = s;
    }
    __syncthreads();
    for (int e = tid; e < 8192; e += 256) {
        int p3 = e & 7, d = e >> 3;
        int i1 = d & 7, i2 = (d >> 3) & 15, i3 = d >> 7;
        float s = 0.f;
        for (int p2 = 0; p2 < 8; ++p2)
            s += t2[(i2 * 8 + i1) * 8 + p2] * c2[p2 * 64 + i3 * 8 + p3];
        Msh[e] = s;
    }
    int n1 = o >> 7, nn = o & 127, n2 = nn >> 3, n3 = nn & 7;
    float v[8];
    for (int p4 = 0; p4 < 8; ++p4) {
        float s = 0.f;
        for (int p5 = 0; p5 < 8; ++p5)
            s += c4[p4 * 128 + n2 * 8 + p5] * c5[p5 * 8 + n3];
        v[p4] = s;
    }
    float ncol[8];
    for (int r3 = 0; r3 < 8; ++r3) {
        float s = 0.f;
        for (int p4 = 0; p4 < 8; ++p4)
            s += c3[r3 * 64 + n1 * 8 + p4] * v[p4];
        ncol[r3] = s;
    }
    __syncthreads();

    int d0 = tid * 4;
    f32x4 w = *(const f32x4*)&W[o * D_DIM + d0];
    bf16x4 res;
    for (int k = 0; k < 4; ++k) {
        float acc = 0.f;
        for (int r = 0; r < 8; ++r)
            acc += Msh[(d0 + k) * 8 + r] * ncol[r];
        res[k] = (bf16)(w[k] + ALPHA_F * acc);
    }
    *(bf16x4*)&Weff[o * D_DIM + d0] = res;
}

extern "C" void kernel_launch(void* const* d_in, const int* in_sizes, int n_in,
                              void* d_out, int out_size, void* d_ws, size_t ws_size,
                              hipStream_t stream) {
    const float* x  = (const float*)d_in[0];
    const float* W  = (const float*)d_in[1];
    const float* b  = (const float*)d_in[2];
    const float* c0 = (const float*)d_in[3];
    const float* c1 = (const float*)d_in[4];
    const float* c2 = (const float*)d_in[5];
    const float* c3 = (const float*)d_in[6];
    const float* c4 = (const float*)d_in[7];
    const float* c5 = (const float*)d_in[8];
    float* out = (float*)d_out;

    // Workspace: Weff bf16 2MB @0 | M 32KB + NT 32KB @2MB | Xb 32MB @4MB
    char* ws = (char*)d_ws;
    bf16*  Weff = (bf16*)ws;
    float* Mws  = (float*)(ws + 2u * 1024u * 1024u);
    float* NTws = Mws + 8192;
    bf16*  Xb   = (bf16*)(ws + 4u * 1024u * 1024u);
    const size_t need = 4u * 1024u * 1024u + (size_t)BS_ROWS * D_DIM * 2u;

    // One-time: raise dynamic-LDS cap for the pipelined GEMM (128 KB).
    static int smem_ok = -1;
    if (smem_ok < 0) {
        hipError_t e = hipFuncSetAttribute((const void*)gemm_pipe4_kernel,
                                           hipFuncAttributeMaxDynamicSharedMemorySize,
                                           2 * BUF4);
        smem_ok = (e == hipSuccess) ? 1 : 0;
    }

    if (ws_size >= need) {
        make_mn_kernel<<<64, 256, 0, stream>>>(c0, c1, c2, c3, c4, c5, Mws, NTws);
        weff_cast_kernel<<<512 + 8192, 256, 0, stream>>>(x, W, Mws, NTws, Weff, Xb);
        if (smem_ok) {
            gemm_pipe4_kernel<<<dim3(256), 512, 2 * BUF4, stream>>>(Xb, Weff, b, out);
        } else {
            dim3 grid(BS_ROWS / BM, D_DIM / BN);
            gemm_bb_kernel<<<grid, 256, 0, stream>>>(Xb, Weff, b, out);
        }
    } else {
        build_weff_fused_kernel<<<D_DIM, 256, 0, stream>>>(W, c0, c1, c2, c3, c4, c5, Weff);
        dim3 grid(BS_ROWS / BM, D_DIM / BN);
        gemm_bias_kernel<<<grid, 256, 0, stream>>>(x, Weff, b, out);
    }
}